// Round 2
// baseline (459.125 us; speedup 1.0000x reference)
//
#include <hip/hip_runtime.h>

typedef __bf16 bf16;
typedef bf16 bf16x4 __attribute__((ext_vector_type(4)));
typedef bf16 bf16x8 __attribute__((ext_vector_type(8)));
typedef float f32x4 __attribute__((ext_vector_type(4)));

#define D_MODEL 1024
#define NHEAD   16
#define D_K     64
#define BATCH   8
#define SEQL    1024
#define MROWS   (BATCH*SEQL)   // 8192

// ---------------- f32 -> bf16 conversion (7 arrays in one launch) ----------------
struct Cvt7 {
    const float* s[7];
    bf16*        d[7];
    int          n[7];
};

__global__ __launch_bounds__(256) void cvt7_kernel(Cvt7 a) {
    const int y = blockIdx.y;
    const float* __restrict__ src = a.s[y];
    bf16* __restrict__ dst = a.d[y];
    const int n4 = a.n[y] >> 2;
    const int stride = gridDim.x * blockDim.x;
    for (int i = blockIdx.x * blockDim.x + threadIdx.x; i < n4; i += stride) {
        float4 v = ((const float4*)src)[i];
        bf16x4 o = { (bf16)v.x, (bf16)v.y, (bf16)v.z, (bf16)v.w };
        ((bf16x4*)dst)[i] = o;
    }
}

// ================= 256x256 tile, BK=32, phase-interleaved counted-vmcnt GEMM =================
// C = A * B^T, A[M,K], B[N,K] bf16 row-major. 8 waves (2 row x 4 col), per-wave 128x64 output.
// LDS 64KB: 2 bufs x (A 16KB + B 16KB). Each 8KB half-tile holds 128 rows x 32 cols in
// permuted-chunk layout: 16B chunk (row,kb) at slot ((row>>4)*64 + (row&15)*4 + kb), so each
// fragment ds_read_b128 covers a contiguous 1KB region -> uniform bank coverage (conflict-free).
// Staging: global_load_lds with linear LDS dest + chunk-permuted per-lane global source.
#define TBM 256
#define TBN 256
#define TBK 32
#define NTILES (D_MODEL / TBK)   // 32

__device__ __forceinline__ void stage_half(const bf16* __restrict__ Mat, int row0, int k0,
                                           char* lds_half, int tid) {
    // thread tid fills 16B slot tid: holds (row = ((tid>>6)<<4)|((tid>>2)&15), kb = tid&3)
    const int row = ((tid >> 6) << 4) | ((tid >> 2) & 15);
    const int kb  = tid & 3;
    const bf16* src = Mat + (size_t)(row0 + row) * D_MODEL + k0 + kb * 8;
    __builtin_amdgcn_global_load_lds(
        (const __attribute__((address_space(1))) unsigned int*)src,
        (__attribute__((address_space(3))) unsigned int*)(lds_half + (tid >> 6) * 1024),
        16, 0, 0);
}

__device__ __forceinline__ void gemm256_core(const bf16* __restrict__ A, const bf16* __restrict__ Bm,
                                             int bm, int bn, char* lds, f32x4 (&acc)[8][4]) {
    const int tid = threadIdx.x;
    const int lane = tid & 63, w = tid >> 6;
    const int wr = w >> 2, wc = w & 3;        // 2 x 4 wave grid
    const int r = lane & 15, kb = lane >> 4;

    // fragment read offsets (chunk layout: byte = rowhi*1024 + rowlo*64 + kb*16)
    const int aoff = wr * 8192 + r * 64 + kb * 16;                              // + m*1024
    const int boff = 16384 + (wc >> 1) * 8192 + (wc & 1) * 4096 + r * 64 + kb * 16;  // + n*1024

    // ---- prologue: stage t0.{B0,B1,A0,A1}, t1.{B0,B1} ----
    stage_half(Bm, bn + 0,   0,   lds + 16384 + 0,    tid);
    stage_half(Bm, bn + 128, 0,   lds + 16384 + 8192, tid);
    stage_half(A,  bm + 0,   0,   lds + 0,            tid);
    stage_half(A,  bm + 128, 0,   lds + 8192,         tid);
    stage_half(Bm, bn + 0,   TBK, lds + 32768 + 16384 + 0,    tid);
    stage_half(Bm, bn + 128, TBK, lds + 32768 + 16384 + 8192, tid);
    asm volatile("s_waitcnt vmcnt(2)" ::: "memory");   // t0 fully staged; t1.B in flight
    __builtin_amdgcn_s_barrier();

    for (int t = 0; t < NTILES; ++t) {
        char* buf   = lds + (t & 1) * 32768;
        char* nbufA = lds + ((t + 1) & 1) * 32768;   // next tile's A region
        char* nnbufB = buf + 16384;                  // tile t+2 shares this buf's B region

        // ---------- phase 0: frag reads (A m0..3 + all B), stage next A, MFMA m0..3 ----------
        bf16x8 am[4], bnf[4];
        #pragma unroll
        for (int m = 0; m < 4; ++m) am[m] = *(const bf16x8*)(buf + aoff + m * 1024);
        #pragma unroll
        for (int n = 0; n < 4; ++n) bnf[n] = *(const bf16x8*)(buf + boff + n * 1024);
        if (t + 1 < NTILES) {
            stage_half(A, bm + 0,   (t + 1) * TBK, nbufA + 0,    tid);
            stage_half(A, bm + 128, (t + 1) * TBK, nbufA + 8192, tid);
        }
        __builtin_amdgcn_s_barrier();
        asm volatile("s_waitcnt lgkmcnt(0)" ::: "memory");
        __builtin_amdgcn_sched_barrier(0);
        __builtin_amdgcn_s_setprio(1);
        #pragma unroll
        for (int m = 0; m < 4; ++m)
            #pragma unroll
            for (int n = 0; n < 4; ++n)
                acc[m][n] = __builtin_amdgcn_mfma_f32_16x16x32_bf16(am[m], bnf[n], acc[m][n], 0, 0, 0);
        __builtin_amdgcn_s_setprio(0);
        __builtin_amdgcn_s_barrier();

        // ---------- phase 1: frag reads (A m4..7), stage t+2 B, counted vmcnt, MFMA m4..7 ----------
        bf16x8 am2[4];
        #pragma unroll
        for (int m = 0; m < 4; ++m) am2[m] = *(const bf16x8*)(buf + aoff + (4 + m) * 1024);
        if (t + 2 < NTILES) {
            stage_half(Bm, bn + 0,   (t + 2) * TBK, nnbufB + 0,    tid);
            stage_half(Bm, bn + 128, (t + 2) * TBK, nnbufB + 8192, tid);
        }
        // FIFO: [t+1.B0,B1 | t+1.A0,A1 | t+2.B0,B1] -> vmcnt(2) completes all of t+1
        if (t < NTILES - 2) asm volatile("s_waitcnt vmcnt(2)" ::: "memory");
        else                asm volatile("s_waitcnt vmcnt(0)" ::: "memory");
        __builtin_amdgcn_s_barrier();
        asm volatile("s_waitcnt lgkmcnt(0)" ::: "memory");
        __builtin_amdgcn_sched_barrier(0);
        __builtin_amdgcn_s_setprio(1);
        #pragma unroll
        for (int m = 0; m < 4; ++m)
            #pragma unroll
            for (int n = 0; n < 4; ++n)
                acc[4 + m][n] = __builtin_amdgcn_mfma_f32_16x16x32_bf16(am2[m], bnf[n], acc[4 + m][n], 0, 0, 0);
        __builtin_amdgcn_s_setprio(0);
        __builtin_amdgcn_s_barrier();
    }
}

// ---------------- Q/K/V projections (one launch, z = 0/1/2) ----------------
__global__ __launch_bounds__(512, 2) void proj3_kernel(
        const bf16* __restrict__ xq, const bf16* __restrict__ xk, const bf16* __restrict__ xv,
        const bf16* __restrict__ Wqb, const bf16* __restrict__ Wkb, const bf16* __restrict__ Wvb,
        const float* __restrict__ bq, const float* __restrict__ bk, const float* __restrict__ bv,
        bf16* __restrict__ Qp, bf16* __restrict__ Kp, bf16* __restrict__ Vt) {
    __shared__ char lds[65536];
    const int z = blockIdx.z;
    const bf16* A    = (z == 0) ? xq  : (z == 1) ? xk  : xv;
    const bf16* Bmat = (z == 0) ? Wqb : (z == 1) ? Wkb : Wvb;
    const float* bias = (z == 0) ? bq : (z == 1) ? bk  : bv;
    const int bm = blockIdx.x * TBM, bn = blockIdx.y * TBN;

    f32x4 acc[8][4] = {};
    gemm256_core(A, Bmat, bm, bn, lds, acc);

    const int lane = threadIdx.x & 63, w = threadIdx.x >> 6;
    const int wr = w >> 2, wc = w & 3, r = lane & 15, g = lane >> 4;
    #pragma unroll
    for (int n = 0; n < 4; ++n) {
        const int col = bn + wc * 64 + n * 16 + r;      // output feature
        const float bvl = bias[col];
        const int h = col >> 6, d = col & 63;
        #pragma unroll
        for (int m = 0; m < 8; ++m) {
            #pragma unroll
            for (int j = 0; j < 4; ++j) {
                const int row = bm + wr * 128 + m * 16 + g * 4 + j;   // token index
                const float v = acc[m][n][j] + bvl;
                const int b = row >> 10, s = row & (SEQL - 1);
                const int bh = b * NHEAD + h;
                if (z == 0) {
                    Qp[((size_t)bh * SEQL + s) * D_K + d] = (bf16)v;
                } else if (z == 1) {
                    Kp[((size_t)bh * SEQL + s) * D_K + d] = (bf16)v;
                } else {
                    Vt[((size_t)bh * D_K + d) * SEQL + s] = (bf16)v;
                }
            }
        }
    }
}

// ---------------- output projection: out = AO * Wo^T + bo (f32 out) ----------------
__global__ __launch_bounds__(512, 2) void outproj_kernel(
        const bf16* __restrict__ AO, const bf16* __restrict__ Wob,
        const float* __restrict__ bo, float* __restrict__ out) {
    __shared__ char lds[65536];
    const int bm = blockIdx.x * TBM, bn = blockIdx.y * TBN;
    f32x4 acc[8][4] = {};
    gemm256_core(AO, Wob, bm, bn, lds, acc);

    const int lane = threadIdx.x & 63, w = threadIdx.x >> 6;
    const int wr = w >> 2, wc = w & 3, r = lane & 15, g = lane >> 4;
    #pragma unroll
    for (int n = 0; n < 4; ++n) {
        const int col = bn + wc * 64 + n * 16 + r;
        const float bvl = bo[col];
        #pragma unroll
        for (int m = 0; m < 8; ++m)
            #pragma unroll
            for (int j = 0; j < 4; ++j) {
                const int row = bm + wr * 128 + m * 16 + g * 4 + j;
                out[(size_t)row * D_MODEL + col] = acc[m][n][j] + bvl;
            }
    }
}

// ---------------- fused masked flash attention (unchanged from R1) ----------------
__global__ __launch_bounds__(256) void attn_kernel(
        const bf16* __restrict__ Qp, const bf16* __restrict__ Kp, const bf16* __restrict__ Vt,
        const unsigned int* __restrict__ mask, bf16* __restrict__ AO) {
    __shared__ bf16 plds[4][16 * 64];    // per-wave P tile (2 KiB each)
    const int bh = blockIdx.y, b = bh >> 4, h = bh & 15;
    const int t = threadIdx.x, lane = t & 63, w = t >> 6;
    const int q0 = blockIdx.x * 64 + w * 16;     // this wave's q-row base
    const int r = lane & 15, g = lane >> 4;

    const bf16* __restrict__ Qh = Qp + ((size_t)bh * SEQL + q0) * D_K;
    const bf16* __restrict__ Kh = Kp + (size_t)bh * SEQL * D_K;
    const bf16* __restrict__ Vh = Vt + (size_t)bh * D_K * SEQL;
    const unsigned int* __restrict__ Mq = mask + ((size_t)bh * SEQL + q0) * SEQL;

    bf16x8 qf[2];
    #pragma unroll
    for (int kk = 0; kk < 2; ++kk)
        qf[kk] = *(const bf16x8*)(Qh + r * D_K + kk * 32 + g * 8);

    f32x4 o[4] = {};
    float mrun[4] = {-1e30f, -1e30f, -1e30f, -1e30f};
    float lrun[4] = {0.f, 0.f, 0.f, 0.f};
    bf16* P = plds[w];

    for (int s0 = 0; s0 < SEQL; s0 += 64) {
        f32x4 sf[4] = {};
        #pragma unroll
        for (int n = 0; n < 4; ++n) {
            #pragma unroll
            for (int kk = 0; kk < 2; ++kk) {
                bf16x8 kf = *(const bf16x8*)(Kh + (size_t)(s0 + n * 16 + r) * D_K + kk * 32 + g * 8);
                sf[n] = __builtin_amdgcn_mfma_f32_16x16x32_bf16(qf[kk], kf, sf[n], 0, 0, 0);
            }
        }
        #pragma unroll
        for (int n = 0; n < 4; ++n)
            #pragma unroll
            for (int j = 0; j < 4; ++j) {
                const unsigned mv = Mq[(size_t)(g * 4 + j) * SEQL + s0 + n * 16 + r];
                sf[n][j] = mv ? sf[n][j] * 0.125f : -1e30f;
            }
        float rsc[4];
        #pragma unroll
        for (int j = 0; j < 4; ++j) {
            float mx = fmaxf(fmaxf(sf[0][j], sf[1][j]), fmaxf(sf[2][j], sf[3][j]));
            #pragma unroll
            for (int dd = 1; dd < 16; dd <<= 1)
                mx = fmaxf(mx, __shfl_xor(mx, dd));
            const float mn = fmaxf(mrun[j], mx);
            rsc[j] = __expf(mrun[j] - mn);
            mrun[j] = mn;
        }
        float ps[4] = {0.f, 0.f, 0.f, 0.f};
        #pragma unroll
        for (int n = 0; n < 4; ++n)
            #pragma unroll
            for (int j = 0; j < 4; ++j) {
                const float p = __expf(sf[n][j] - mrun[j]);
                sf[n][j] = p;
                ps[j] += p;
            }
        #pragma unroll
        for (int j = 0; j < 4; ++j) {
            #pragma unroll
            for (int dd = 1; dd < 16; dd <<= 1)
                ps[j] += __shfl_xor(ps[j], dd);
            lrun[j] = lrun[j] * rsc[j] + ps[j];
        }
        #pragma unroll
        for (int n = 0; n < 4; ++n)
            #pragma unroll
            for (int j = 0; j < 4; ++j)
                o[n][j] *= rsc[j];
        #pragma unroll
        for (int n = 0; n < 4; ++n)
            #pragma unroll
            for (int j = 0; j < 4; ++j) {
                const int q = g * 4 + j, kv = n * 16 + r;
                const int byteoff = (q * 128 + kv * 2) ^ ((q & 7) << 4);
                *(bf16*)((char*)P + byteoff) = (bf16)sf[n][j];
            }
        asm volatile("s_waitcnt lgkmcnt(0)" ::: "memory");
        __builtin_amdgcn_sched_barrier(0);
        #pragma unroll
        for (int kk = 0; kk < 2; ++kk) {
            const int byteoff = (r * 128 + (kk * 32 + g * 8) * 2) ^ ((r & 7) << 4);
            bf16x8 pf = *(const bf16x8*)((char*)P + byteoff);
            #pragma unroll
            for (int n = 0; n < 4; ++n) {
                bf16x8 vf = *(const bf16x8*)(Vh + (size_t)(n * 16 + r) * SEQL + s0 + kk * 32 + g * 8);
                o[n] = __builtin_amdgcn_mfma_f32_16x16x32_bf16(pf, vf, o[n], 0, 0, 0);
            }
        }
    }
    #pragma unroll
    for (int j = 0; j < 4; ++j) {
        const float inv = 1.0f / lrun[j];
        const int q = q0 + g * 4 + j;
        #pragma unroll
        for (int n = 0; n < 4; ++n) {
            const int d = n * 16 + r;
            AO[((size_t)(b * SEQL + q)) * D_MODEL + h * D_K + d] = (bf16)(o[n][j] * inv);
        }
    }
}

// ---------------- launch ----------------
extern "C" void kernel_launch(void* const* d_in, const int* in_sizes, int n_in,
                              void* d_out, int out_size, void* d_ws, size_t ws_size,
                              hipStream_t stream) {
    const float* q    = (const float*)d_in[0];
    const float* k    = (const float*)d_in[1];
    const float* v    = (const float*)d_in[2];
    const unsigned int* mask = (const unsigned int*)d_in[3];
    const float* Wq = (const float*)d_in[4];
    const float* bq = (const float*)d_in[5];
    const float* Wk = (const float*)d_in[6];
    const float* bk = (const float*)d_in[7];
    const float* Wv = (const float*)d_in[8];
    const float* bv = (const float*)d_in[9];
    const float* Wo = (const float*)d_in[10];
    const float* bo = (const float*)d_in[11];

    char* ws = (char*)d_ws;
    const size_t MB = 1u << 20;
    bf16* qb  = (bf16*)(ws + 0 * MB);
    bf16* kb  = (bf16*)(ws + 16 * MB);
    bf16* vb  = (bf16*)(ws + 32 * MB);
    bf16* Wqb = (bf16*)(ws + 48 * MB);
    bf16* Wkb = (bf16*)(ws + 50 * MB);
    bf16* Wvb = (bf16*)(ws + 52 * MB);
    bf16* Wob = (bf16*)(ws + 54 * MB);
    bf16* Qp  = (bf16*)(ws + 56 * MB);
    bf16* Kp  = (bf16*)(ws + 72 * MB);
    bf16* Vt  = (bf16*)(ws + 88 * MB);
    bf16* AO  = (bf16*)(ws + 104 * MB);   // 120 MiB total

    Cvt7 c;
    c.s[0] = q;  c.d[0] = qb;  c.n[0] = MROWS * D_MODEL;
    c.s[1] = k;  c.d[1] = kb;  c.n[1] = MROWS * D_MODEL;
    c.s[2] = v;  c.d[2] = vb;  c.n[2] = MROWS * D_MODEL;
    c.s[3] = Wq; c.d[3] = Wqb; c.n[3] = D_MODEL * D_MODEL;
    c.s[4] = Wk; c.d[4] = Wkb; c.n[4] = D_MODEL * D_MODEL;
    c.s[5] = Wv; c.d[5] = Wvb; c.n[5] = D_MODEL * D_MODEL;
    c.s[6] = Wo; c.d[6] = Wob; c.n[6] = D_MODEL * D_MODEL;
    cvt7_kernel<<<dim3(1024, 7), 256, 0, stream>>>(c);

    proj3_kernel<<<dim3(MROWS / TBM, D_MODEL / TBN, 3), 512, 0, stream>>>(
        qb, kb, vb, Wqb, Wkb, Wvb, bq, bk, bv, Qp, Kp, Vt);

    attn_kernel<<<dim3(SEQL / 64, BATCH * NHEAD), 256, 0, stream>>>(Qp, Kp, Vt, mask, AO);

    outproj_kernel<<<dim3(MROWS / TBM, D_MODEL / TBN), 512, 0, stream>>>(AO, Wob, bo, (float*)d_out);
}